// Round 18
// baseline (264.514 us; speedup 1.0000x reference)
//
#include <hip/hip_runtime.h>
#include <hip/hip_bf16.h>

#define N 8192
#define FIN 128
#define FOUT 64
#define CSPLIT 4
#define CHUNK (N / CSPLIT)     // 2048 cols per block
#define M 32                   // rows per block
#define TILE 64                // cols per tile
#define NT (CHUNK / TILE)      // 32 tiles
#define LOG2E 1.44269504f

typedef __attribute__((ext_vector_type(4))) float f32x4;
typedef __attribute__((ext_vector_type(4))) int i32x4;
typedef __attribute__((ext_vector_type(8))) short bf16x8;

#define GLOAD_LDS16(gp, lp)                                                    \
    __builtin_amdgcn_global_load_lds(                                          \
        (const __attribute__((address_space(1))) void*)(gp),                   \
        (__attribute__((address_space(3))) void*)(lp), 16, 0, 0)

// Kernel 1: Wh = h @ W (W staged once per 16 rows; R13-verified layout),
// s_src/s_dst PRE-SCALED by log2(e). Also zeroes the per-rowgroup counters
// (256 ints) used by gat_partial's fused finalize -- runs before gat on the
// same stream, so ordering/visibility is guaranteed.
__global__ __launch_bounds__(256) void wh_kernel(
    const float* __restrict__ h, const float* __restrict__ W,
    const float* __restrict__ a,
    __hip_bfloat16* __restrict__ whT, float* __restrict__ s_src,
    float* __restrict__ s_dst, int* __restrict__ cnt) {
    __shared__ float Wl[FIN * FOUT];              // 32 KB
    const int w = threadIdx.x >> 6;
    const int lane = threadIdx.x & 63;            // lane = output feature f
    if (threadIdx.x == 0 && blockIdx.x < (N / M)) cnt[blockIdx.x] = 0;
#pragma unroll
    for (int q = 0; q < 8; ++q) {
        const int i = w * 8 + q;
        GLOAD_LDS16(W + i * 256 + lane * 4, &Wl[i * 256]);
    }
    asm volatile("s_waitcnt vmcnt(0)" ::: "memory");
    __syncthreads();

    const int rbase = blockIdx.x * 16 + w * 4;    // 4 rows per wave
    float acc[4] = {0.f, 0.f, 0.f, 0.f};
    for (int k0 = 0; k0 < FIN; k0 += 4) {
        float wv0 = Wl[(k0 + 0) * FOUT + lane];
        float wv1 = Wl[(k0 + 1) * FOUT + lane];
        float wv2 = Wl[(k0 + 2) * FOUT + lane];
        float wv3 = Wl[(k0 + 3) * FOUT + lane];
#pragma unroll
        for (int rr = 0; rr < 4; ++rr) {
            f32x4 hv = *(const f32x4*)(h + (size_t)(rbase + rr) * FIN + k0);
            acc[rr] += hv[0] * wv0 + hv[1] * wv1 + hv[2] * wv2 + hv[3] * wv3;
        }
    }
#pragma unroll
    for (int rr = 0; rr < 4; ++rr) {
        const int row = rbase + rr;
        whT[(size_t)lane * N + row] = __float2bfloat16(acc[rr]);
        float s1 = acc[rr] * a[lane];
        float s2 = acc[rr] * a[FOUT + lane];
#pragma unroll
        for (int mm = 32; mm >= 1; mm >>= 1) {
            s1 += __shfl_xor(s1, mm, 64);
            s2 += __shfl_xor(s2, mm, 64);
        }
        if (lane == 0) { s_src[row] = s1 * LOG2E; s_dst[row] = s2 * LOG2E; }
    }
}

// Kernel 2: fused masked-softmax attention, R16 structure VERBATIM (verified:
// 4 blocks/CU, one barrier per tile, stage(t+1) before compute(t)), plus a
// fused finalize: last of the 4 chunk-blocks per rowgroup (device-scope
// threadfence-reduction pattern) sums partials, divides, ELUs, stores out.
__global__ __launch_bounds__(256, 4) void gat_partial(
    const int* __restrict__ adj, const __hip_bfloat16* __restrict__ whT,
    const float* __restrict__ s_src, const float* __restrict__ s_dst,
    float* __restrict__ numP, float* __restrict__ denP,
    int* __restrict__ cnt, float* __restrict__ out) {
    union SMem {
        struct {
            int adjb[2][M][TILE];       // 16 KB (256B rows, swizzled)
            short whb[2][FOUT][TILE];   // 16 KB (128B rows, swizzled)
            float sdl[CHUNK];           // 8 KB
        } s;                            // 40960 B exactly -> 4 blocks/CU
        struct { float pC[2][M][FOUT]; float pD[2][M]; } e;  // 16.25 KB
    };
    __shared__ SMem sm;

    const int tid = threadIdx.x;
    const int w = tid >> 6, lane = tid & 63;
    const int m = lane & 15, kg = lane >> 4;
    const int wr = w >> 1, wc = w & 1;
    const int rg = blockIdx.x >> 2;
    const int c = blockIdx.x & 3;
    const int ibase = rg * M;
    const int cb = c * CHUNK;
    const int aRow = wr * 16 + m;
    const float ssrc = s_src[ibase + aRow];       // pre-scaled by log2e
    const int sidx = w * 2;                       // 2 staging instrs per wave/array

    f32x4 acc[4] = {{0,0,0,0},{0,0,0,0},{0,0,0,0},{0,0,0,0}};
    f32x4 acc4 = {0,0,0,0};                       // denominator accumulator
    const short oneb = (m == 0) ? (short)0x3F80 : (short)0;
    const bf16x8 bones = {oneb, oneb, oneb, oneb, oneb, oneb, oneb, oneb};

    // stage tile t into buf: 2 adj + 2 wh instrs per wave (uniform = 4)
    auto stage = [&](int t, int buf) {
        const int gcol = cb + t * TILE;
#pragma unroll
        for (int q = 0; q < 2; ++q) {          // adj: instr covers 4 rows (1 KB)
            const int idx = sidx + q;          // 0..7
            const int r = idx * 4 + (lane >> 4);
            const int b = ((lane & 15) * 16) ^ ((r & 15) << 4);   // byte in 256B row
            GLOAD_LDS16(adj + (size_t)(ibase + r) * N + gcol + (b >> 2),
                        &sm.s.adjb[buf][idx * 4][0]);
        }
#pragma unroll
        for (int q = 0; q < 2; ++q) {          // wh: instr covers 8 feat rows (1 KB)
            const int idx = sidx + q;          // 0..7
            const int f = idx * 8 + (lane >> 3);
            const int b = ((lane & 7) * 16) ^ ((f & 7) << 4);     // byte in 128B row
            GLOAD_LDS16(whT + (size_t)f * N + gcol + (b >> 1),
                        &sm.s.whb[buf][idx * 8][0]);
        }
    };

    // prologue: sdl chunk (2 instrs/wave = full 8 KB) + tile 0; drain; barrier
#pragma unroll
    for (int q = 0; q < 2; ++q) {
        const int i = sidx + q;                // 0..7 -> 8 x 256 floats = 2048
        GLOAD_LDS16(s_dst + cb + i * 256 + lane * 4, &sm.s.sdl[i * 256]);
    }
    stage(0, 0);
    asm volatile("s_waitcnt vmcnt(0)" ::: "memory");
    __builtin_amdgcn_s_barrier();

    for (int t = 0; t < NT; ++t) {
        const int buf = t & 1;
        if (t + 1 < NT) stage(t + 1, buf ^ 1);   // issue BEFORE compute

        // ---- compute tile t (LDS only) ----
        {
            const int kcol = wc * 32 + kg * 8;   // 0..56 within 64-col tile
            const char* adjbase = (const char*)&sm.s.adjb[buf][0][0];
            const int aswz = (aRow & 15) << 4;
            i32x4 a0 = *(const i32x4*)(adjbase + aRow * 256 + ((kcol * 4) ^ aswz));
            i32x4 a1 = *(const i32x4*)(adjbase + aRow * 256 + ((kcol * 4 + 16) ^ aswz));
            f32x4 d0 = *(const f32x4*)&sm.s.sdl[t * TILE + kcol];
            f32x4 d1 = *(const f32x4*)&sm.s.sdl[t * TILE + kcol + 4];
            const char* whbase = (const char*)&sm.s.whb[buf][0][0];
            const int wswz = (m & 7) << 4;
            bf16x8 bq0 = *(const bf16x8*)(whbase + (0 * 16 + m) * 128 + ((kcol * 2) ^ wswz));
            bf16x8 bq1 = *(const bf16x8*)(whbase + (1 * 16 + m) * 128 + ((kcol * 2) ^ wswz));
            bf16x8 bq2 = *(const bf16x8*)(whbase + (2 * 16 + m) * 128 + ((kcol * 2) ^ wswz));
            bf16x8 bq3 = *(const bf16x8*)(whbase + (3 * 16 + m) * 128 + ((kcol * 2) ^ wswz));

            float p[8];
#pragma unroll
            for (int e = 0; e < 4; ++e) {
                float x = ssrc + d0[e];
                float xl = fmaxf(x, 0.2f * x);
                float pe;
                asm("v_exp_f32 %0, %1" : "=v"(pe) : "v"(xl));
                p[e] = (a0[e] != 0) ? pe : 0.f;
            }
#pragma unroll
            for (int e = 0; e < 4; ++e) {
                float x = ssrc + d1[e];
                float xl = fmaxf(x, 0.2f * x);
                float pe;
                asm("v_exp_f32 %0, %1" : "=v"(pe) : "v"(xl));
                p[4 + e] = (a1[e] != 0) ? pe : 0.f;
            }
            union { bf16x8 v; unsigned u[4]; } afr;
#pragma unroll
            for (int q = 0; q < 4; ++q) {
                asm("v_cvt_pk_bf16_f32 %0, %1, %2"
                    : "=v"(afr.u[q]) : "v"(p[2 * q]), "v"(p[2 * q + 1]));
            }

            acc[0] = __builtin_amdgcn_mfma_f32_16x16x32_bf16(afr.v, bq0, acc[0], 0, 0, 0);
            acc[1] = __builtin_amdgcn_mfma_f32_16x16x32_bf16(afr.v, bq1, acc[1], 0, 0, 0);
            acc[2] = __builtin_amdgcn_mfma_f32_16x16x32_bf16(afr.v, bq2, acc[2], 0, 0, 0);
            acc[3] = __builtin_amdgcn_mfma_f32_16x16x32_bf16(afr.v, bq3, acc[3], 0, 0, 0);
            acc4   = __builtin_amdgcn_mfma_f32_16x16x32_bf16(afr.v, bones, acc4, 0, 0, 0);
        }

        // stage(t+1) had the whole compute phase to land; drain residue.
        asm volatile("s_waitcnt vmcnt(0)" ::: "memory");
        __builtin_amdgcn_s_barrier();
    }

    // epilogue (last barrier passed -> safe to reuse LDS)
#pragma unroll
    for (int r = 0; r < 4; ++r) {
#pragma unroll
        for (int q = 0; q < 4; ++q) {
            sm.e.pC[wc][wr * 16 + kg * 4 + r][q * 16 + m] = acc[q][r];
        }
    }
    if (m == 0) {   // den (col 0 of ones-MFMA): m==0 lanes, row kg*4+r
#pragma unroll
        for (int r = 0; r < 4; ++r) {
            sm.e.pD[wc][wr * 16 + kg * 4 + r] = acc4[r];
        }
    }
    __syncthreads();

    float* numC = numP + (size_t)c * N * FOUT;
    float* denC = denP + (size_t)c * N;
#pragma unroll
    for (int k = 0; k < 8; ++k) {
        int idx = k * 256 + tid;
        int i = idx >> 6, f = idx & 63;
        float num = sm.e.pC[0][i][f] + sm.e.pC[1][i][f];
        numC[(size_t)(ibase + i) * FOUT + f] = num;
        if (f == 0) {
            denC[ibase + i] = sm.e.pD[0][i] + sm.e.pD[1][i];
        }
    }

    // ---- fused finalize: threadfence-reduction, last block of the 4 chunks ----
    __threadfence();                 // make this block's partials device-visible
    __syncthreads();                 // all threads' stores fenced, LDS reads done
    int* flagp = (int*)&sm;          // LDS dead -> reuse one word as the flag
    if (tid == 0) {
        int old = atomicAdd(&cnt[rg], 1);
        *flagp = (old == CSPLIT - 1) ? 1 : 0;
    }
    __syncthreads();
    if (*flagp) {
        __threadfence();             // acquire: see other chunks' partials
#pragma unroll
        for (int k = 0; k < 8; ++k) {
            int idx = k * 256 + tid;
            int i = idx >> 6, f = idx & 63;
            float num = 0.f, den = 0.f;
#pragma unroll
            for (int cc = 0; cc < CSPLIT; ++cc) {
                num += numP[(size_t)cc * N * FOUT + (size_t)(ibase + i) * FOUT + f];
                den += denP[(size_t)cc * N + ibase + i];
            }
            float v = num / den;
            out[(size_t)(ibase + i) * FOUT + f] = (v > 0.f) ? v : expm1f(v);
        }
    }
}

extern "C" void kernel_launch(void* const* d_in, const int* in_sizes, int n_in,
                              void* d_out, int out_size, void* d_ws, size_t ws_size,
                              hipStream_t stream) {
    const float* h = (const float*)d_in[0];
    const int* adj = (const int*)d_in[1];
    const float* W = (const float*)d_in[2];
    const float* a = (const float*)d_in[3];
    float* out = (float*)d_out;

    char* ws = (char*)d_ws;
    __hip_bfloat16* whT = (__hip_bfloat16*)ws;                       // 1 MB
    float* s_src = (float*)(ws + (size_t)FOUT * N * sizeof(__hip_bfloat16));
    float* s_dst = s_src + N;                                        // +32 KB each
    float* numP = s_dst + N;                                         // 8 MB
    float* denP = numP + (size_t)CSPLIT * N * FOUT;                  // 128 KB
    int* cnt = (int*)(denP + (size_t)CSPLIT * N);                    // 1 KB

    hipLaunchKernelGGL(wh_kernel, dim3(N / 16), dim3(256), 0, stream,
                       h, W, a, whT, s_src, s_dst, cnt);
    hipLaunchKernelGGL(gat_partial, dim3((N / M) * CSPLIT), dim3(256), 0, stream,
                       adj, whT, s_src, s_dst, numP, denP, cnt, out);
}

// Round 19
// 85.101 us; speedup vs baseline: 3.1083x; 3.1083x over previous
//
#include <hip/hip_runtime.h>
#include <hip/hip_bf16.h>

#define N 8192
#define FIN 128
#define FOUT 64
#define CSPLIT 4
#define CHUNK (N / CSPLIT)     // 2048 cols per block
#define M 32                   // rows per block
#define TILE 64                // cols per tile
#define NT (CHUNK / TILE)      // 32 tiles
#define LOG2E 1.44269504f

typedef __attribute__((ext_vector_type(4))) float f32x4;
typedef __attribute__((ext_vector_type(4))) int i32x4;
typedef __attribute__((ext_vector_type(8))) short bf16x8;

#define GLOAD_LDS16(gp, lp)                                                    \
    __builtin_amdgcn_global_load_lds(                                          \
        (const __attribute__((address_space(1))) void*)(gp),                   \
        (__attribute__((address_space(3))) void*)(lp), 16, 0, 0)

// Kernel 1: Wh = h @ W (W staged once per 16 rows; verified R13/R18),
// s_src/s_dst PRE-SCALED by log2(e).
__global__ __launch_bounds__(256) void wh_kernel(
    const float* __restrict__ h, const float* __restrict__ W,
    const float* __restrict__ a,
    __hip_bfloat16* __restrict__ whT, float* __restrict__ s_src,
    float* __restrict__ s_dst) {
    __shared__ float Wl[FIN * FOUT];              // 32 KB
    const int w = threadIdx.x >> 6;
    const int lane = threadIdx.x & 63;            // lane = output feature f
#pragma unroll
    for (int q = 0; q < 8; ++q) {
        const int i = w * 8 + q;
        GLOAD_LDS16(W + i * 256 + lane * 4, &Wl[i * 256]);
    }
    asm volatile("s_waitcnt vmcnt(0)" ::: "memory");
    __syncthreads();

    const int rbase = blockIdx.x * 16 + w * 4;    // 4 rows per wave
    float acc[4] = {0.f, 0.f, 0.f, 0.f};
    for (int k0 = 0; k0 < FIN; k0 += 4) {
        float wv0 = Wl[(k0 + 0) * FOUT + lane];
        float wv1 = Wl[(k0 + 1) * FOUT + lane];
        float wv2 = Wl[(k0 + 2) * FOUT + lane];
        float wv3 = Wl[(k0 + 3) * FOUT + lane];
#pragma unroll
        for (int rr = 0; rr < 4; ++rr) {
            f32x4 hv = *(const f32x4*)(h + (size_t)(rbase + rr) * FIN + k0);
            acc[rr] += hv[0] * wv0 + hv[1] * wv1 + hv[2] * wv2 + hv[3] * wv3;
        }
    }
#pragma unroll
    for (int rr = 0; rr < 4; ++rr) {
        const int row = rbase + rr;
        whT[(size_t)lane * N + row] = __float2bfloat16(acc[rr]);
        float s1 = acc[rr] * a[lane];
        float s2 = acc[rr] * a[FOUT + lane];
#pragma unroll
        for (int mm = 32; mm >= 1; mm >>= 1) {
            s1 += __shfl_xor(s1, mm, 64);
            s2 += __shfl_xor(s2, mm, 64);
        }
        if (lane == 0) { s_src[row] = s1 * LOG2E; s_dst[row] = s2 * LOG2E; }
    }
}

// Kernel 2: fused masked-softmax attention partials -- R16 structure VERBATIM
// (best verified: 75.1 us total). 4 blocks/CU, one barrier per tile,
// stage(t+1) issued BEFORE compute(t), vmcnt(0)+barrier after.
__global__ __launch_bounds__(256, 4) void gat_partial(
    const int* __restrict__ adj, const __hip_bfloat16* __restrict__ whT,
    const float* __restrict__ s_src, const float* __restrict__ s_dst,
    float* __restrict__ numP, float* __restrict__ denP) {
    union SMem {
        struct {
            int adjb[2][M][TILE];       // 16 KB (256B rows, swizzled)
            short whb[2][FOUT][TILE];   // 16 KB (128B rows, swizzled)
            float sdl[CHUNK];           // 8 KB
        } s;                            // 40960 B exactly -> 4 blocks/CU
        struct { float pC[2][M][FOUT]; float pD[2][M]; } e;  // 16.25 KB
    };
    __shared__ SMem sm;

    const int tid = threadIdx.x;
    const int w = tid >> 6, lane = tid & 63;
    const int m = lane & 15, kg = lane >> 4;
    const int wr = w >> 1, wc = w & 1;
    const int rg = blockIdx.x >> 2;
    const int c = blockIdx.x & 3;
    const int ibase = rg * M;
    const int cb = c * CHUNK;
    const int aRow = wr * 16 + m;
    const float ssrc = s_src[ibase + aRow];       // pre-scaled by log2e
    const int sidx = w * 2;                       // 2 staging instrs per wave/array

    f32x4 acc[4] = {{0,0,0,0},{0,0,0,0},{0,0,0,0},{0,0,0,0}};
    f32x4 acc4 = {0,0,0,0};                       // denominator accumulator
    const short oneb = (m == 0) ? (short)0x3F80 : (short)0;
    const bf16x8 bones = {oneb, oneb, oneb, oneb, oneb, oneb, oneb, oneb};

    // stage tile t into buf: 2 adj + 2 wh instrs per wave (uniform = 4)
    auto stage = [&](int t, int buf) {
        const int gcol = cb + t * TILE;
#pragma unroll
        for (int q = 0; q < 2; ++q) {          // adj: instr covers 4 rows (1 KB)
            const int idx = sidx + q;          // 0..7
            const int r = idx * 4 + (lane >> 4);
            const int b = ((lane & 15) * 16) ^ ((r & 15) << 4);   // byte in 256B row
            GLOAD_LDS16(adj + (size_t)(ibase + r) * N + gcol + (b >> 2),
                        &sm.s.adjb[buf][idx * 4][0]);
        }
#pragma unroll
        for (int q = 0; q < 2; ++q) {          // wh: instr covers 8 feat rows (1 KB)
            const int idx = sidx + q;          // 0..7
            const int f = idx * 8 + (lane >> 3);
            const int b = ((lane & 7) * 16) ^ ((f & 7) << 4);     // byte in 128B row
            GLOAD_LDS16(whT + (size_t)f * N + gcol + (b >> 1),
                        &sm.s.whb[buf][idx * 8][0]);
        }
    };

    // prologue: sdl chunk (2 instrs/wave = full 8 KB) + tile 0; drain; barrier
#pragma unroll
    for (int q = 0; q < 2; ++q) {
        const int i = sidx + q;                // 0..7 -> 8 x 256 floats = 2048
        GLOAD_LDS16(s_dst + cb + i * 256 + lane * 4, &sm.s.sdl[i * 256]);
    }
    stage(0, 0);
    asm volatile("s_waitcnt vmcnt(0)" ::: "memory");
    __builtin_amdgcn_s_barrier();

    for (int t = 0; t < NT; ++t) {
        const int buf = t & 1;
        if (t + 1 < NT) stage(t + 1, buf ^ 1);   // issue BEFORE compute

        // ---- compute tile t (LDS only) ----
        {
            const int kcol = wc * 32 + kg * 8;   // 0..56 within 64-col tile
            const char* adjbase = (const char*)&sm.s.adjb[buf][0][0];
            const int aswz = (aRow & 15) << 4;
            i32x4 a0 = *(const i32x4*)(adjbase + aRow * 256 + ((kcol * 4) ^ aswz));
            i32x4 a1 = *(const i32x4*)(adjbase + aRow * 256 + ((kcol * 4 + 16) ^ aswz));
            f32x4 d0 = *(const f32x4*)&sm.s.sdl[t * TILE + kcol];
            f32x4 d1 = *(const f32x4*)&sm.s.sdl[t * TILE + kcol + 4];
            const char* whbase = (const char*)&sm.s.whb[buf][0][0];
            const int wswz = (m & 7) << 4;
            bf16x8 bq0 = *(const bf16x8*)(whbase + (0 * 16 + m) * 128 + ((kcol * 2) ^ wswz));
            bf16x8 bq1 = *(const bf16x8*)(whbase + (1 * 16 + m) * 128 + ((kcol * 2) ^ wswz));
            bf16x8 bq2 = *(const bf16x8*)(whbase + (2 * 16 + m) * 128 + ((kcol * 2) ^ wswz));
            bf16x8 bq3 = *(const bf16x8*)(whbase + (3 * 16 + m) * 128 + ((kcol * 2) ^ wswz));

            float p[8];
#pragma unroll
            for (int e = 0; e < 4; ++e) {
                float x = ssrc + d0[e];
                float xl = fmaxf(x, 0.2f * x);
                float pe;
                asm("v_exp_f32 %0, %1" : "=v"(pe) : "v"(xl));
                p[e] = (a0[e] != 0) ? pe : 0.f;
            }
#pragma unroll
            for (int e = 0; e < 4; ++e) {
                float x = ssrc + d1[e];
                float xl = fmaxf(x, 0.2f * x);
                float pe;
                asm("v_exp_f32 %0, %1" : "=v"(pe) : "v"(xl));
                p[4 + e] = (a1[e] != 0) ? pe : 0.f;
            }
            union { bf16x8 v; unsigned u[4]; } afr;
#pragma unroll
            for (int q = 0; q < 4; ++q) {
                asm("v_cvt_pk_bf16_f32 %0, %1, %2"
                    : "=v"(afr.u[q]) : "v"(p[2 * q]), "v"(p[2 * q + 1]));
            }

            acc[0] = __builtin_amdgcn_mfma_f32_16x16x32_bf16(afr.v, bq0, acc[0], 0, 0, 0);
            acc[1] = __builtin_amdgcn_mfma_f32_16x16x32_bf16(afr.v, bq1, acc[1], 0, 0, 0);
            acc[2] = __builtin_amdgcn_mfma_f32_16x16x32_bf16(afr.v, bq2, acc[2], 0, 0, 0);
            acc[3] = __builtin_amdgcn_mfma_f32_16x16x32_bf16(afr.v, bq3, acc[3], 0, 0, 0);
            acc4   = __builtin_amdgcn_mfma_f32_16x16x32_bf16(afr.v, bones, acc4, 0, 0, 0);
        }

        // stage(t+1) had the whole compute phase to land; drain residue.
        asm volatile("s_waitcnt vmcnt(0)" ::: "memory");
        __builtin_amdgcn_s_barrier();
    }

    // epilogue (last barrier passed -> safe to reuse LDS)
#pragma unroll
    for (int r = 0; r < 4; ++r) {
#pragma unroll
        for (int q = 0; q < 4; ++q) {
            sm.e.pC[wc][wr * 16 + kg * 4 + r][q * 16 + m] = acc[q][r];
        }
    }
    if (m == 0) {   // den (col 0 of ones-MFMA): m==0 lanes, row kg*4+r
#pragma unroll
        for (int r = 0; r < 4; ++r) {
            sm.e.pD[wc][wr * 16 + kg * 4 + r] = acc4[r];
        }
    }
    __syncthreads();

    float* numC = numP + (size_t)c * N * FOUT;
    float* denC = denP + (size_t)c * N;
#pragma unroll
    for (int k = 0; k < 8; ++k) {
        int idx = k * 256 + tid;
        int i = idx >> 6, f = idx & 63;
        float num = sm.e.pC[0][i][f] + sm.e.pC[1][i][f];
        numC[(size_t)(ibase + i) * FOUT + f] = num;
        if (f == 0) {
            denC[ibase + i] = sm.e.pD[0][i] + sm.e.pD[1][i];
        }
    }
}

// Kernel 3: sum chunk partials, divide, ELU, store.
__global__ __launch_bounds__(256) void gat_combine(
    const float* __restrict__ numP, const float* __restrict__ denP,
    float* __restrict__ out) {
    int idx = blockIdx.x * 256 + threadIdx.x;
    int row = idx >> 6;
    float num = 0.f, den = 0.f;
#pragma unroll
    for (int cc = 0; cc < CSPLIT; ++cc) {
        num += numP[(size_t)cc * N * FOUT + idx];
        den += denP[(size_t)cc * N + row];
    }
    float v = num / den;
    out[idx] = (v > 0.f) ? v : expm1f(v);
}

extern "C" void kernel_launch(void* const* d_in, const int* in_sizes, int n_in,
                              void* d_out, int out_size, void* d_ws, size_t ws_size,
                              hipStream_t stream) {
    const float* h = (const float*)d_in[0];
    const int* adj = (const int*)d_in[1];
    const float* W = (const float*)d_in[2];
    const float* a = (const float*)d_in[3];
    float* out = (float*)d_out;

    char* ws = (char*)d_ws;
    __hip_bfloat16* whT = (__hip_bfloat16*)ws;                       // 1 MB
    float* s_src = (float*)(ws + (size_t)FOUT * N * sizeof(__hip_bfloat16));
    float* s_dst = s_src + N;                                        // +32 KB each
    float* numP = s_dst + N;                                         // 8 MB
    float* denP = numP + (size_t)CSPLIT * N * FOUT;                  // 128 KB

    hipLaunchKernelGGL(wh_kernel, dim3(N / 16), dim3(256), 0, stream,
                       h, W, a, whT, s_src, s_dst);
    hipLaunchKernelGGL(gat_partial, dim3((N / M) * CSPLIT), dim3(256), 0, stream,
                       adj, whT, s_src, s_dst, numP, denP);
    hipLaunchKernelGGL(gat_combine, dim3(N * FOUT / 256), dim3(256), 0, stream,
                       numP, denP, out);
}

// Round 20
// 74.858 us; speedup vs baseline: 3.5336x; 1.1368x over previous
//
#include <hip/hip_runtime.h>
#include <hip/hip_bf16.h>

#define N 8192
#define FIN 128
#define FOUT 64
#define CSPLIT 4
#define CHUNK (N / CSPLIT)     // 2048 cols per block
#define M 32                   // rows per block
#define TILE 64                // cols per tile
#define NT (CHUNK / TILE)      // 32 tiles
#define LOG2E 1.44269504f

typedef __attribute__((ext_vector_type(4))) float f32x4;
typedef __attribute__((ext_vector_type(4))) int i32x4;
typedef __attribute__((ext_vector_type(8))) short bf16x8;

#define GLOAD_LDS16(gp, lp)                                                    \
    __builtin_amdgcn_global_load_lds(                                          \
        (const __attribute__((address_space(1))) void*)(gp),                   \
        (__attribute__((address_space(3))) void*)(lp), 16, 0, 0)

// Kernel 1: Wh = h @ W (W staged in LDS), s_src/s_dst PRE-SCALED by log2(e).
// 2048 blocks x 4 rows -- empirically the best wh shape (R16: 75.1 total;
// R19's 512-block variant regressed to 85).
__global__ __launch_bounds__(256) void wh_kernel(
    const float* __restrict__ h, const float* __restrict__ W,
    const float* __restrict__ a,
    __hip_bfloat16* __restrict__ whT, float* __restrict__ s_src,
    float* __restrict__ s_dst) {
    __shared__ float Wl[FIN * FOUT];              // 32 KB
    const int w = threadIdx.x >> 6;
    const int lane = threadIdx.x & 63;            // lane = output feature f
#pragma unroll
    for (int q = 0; q < 8; ++q) {
        const int i = w * 8 + q;
        GLOAD_LDS16(W + i * 256 + lane * 4, &Wl[i * 256]);
    }
    asm volatile("s_waitcnt vmcnt(0)" ::: "memory");
    __syncthreads();

    const int row = blockIdx.x * 4 + w;
    const float* hr = h + (size_t)row * FIN;
    float acc = 0.f;
#pragma unroll
    for (int k0 = 0; k0 < FIN; k0 += 4) {
        f32x4 hv = *(const f32x4*)(hr + k0);      // wave-uniform -> broadcast
        acc += hv[0] * Wl[(k0 + 0) * FOUT + lane];
        acc += hv[1] * Wl[(k0 + 1) * FOUT + lane];
        acc += hv[2] * Wl[(k0 + 2) * FOUT + lane];
        acc += hv[3] * Wl[(k0 + 3) * FOUT + lane];
    }
    whT[(size_t)lane * N + row] = __float2bfloat16(acc);
    float s1 = acc * a[lane];
    float s2 = acc * a[FOUT + lane];
#pragma unroll
    for (int mm = 32; mm >= 1; mm >>= 1) {
        s1 += __shfl_xor(s1, mm, 64);
        s2 += __shfl_xor(s2, mm, 64);
    }
    if (lane == 0) { s_src[row] = s1 * LOG2E; s_dst[row] = s2 * LOG2E; }
}

// Kernel 2: fused masked-softmax attention partials (R16 verified structure).
// 256-thread blocks (4 waves), TILE=64, 40 KB LDS -> 4 blocks/CU (4 independent
// barrier domains per CU). One barrier per tile: stage(t+1) issued BEFORE
// compute(t); vmcnt(0)+barrier after. Both-sides XOR swizzles (verified).
__global__ __launch_bounds__(256, 4) void gat_partial(
    const int* __restrict__ adj, const __hip_bfloat16* __restrict__ whT,
    const float* __restrict__ s_src, const float* __restrict__ s_dst,
    float* __restrict__ numP, float* __restrict__ denP) {
    union SMem {
        struct {
            int adjb[2][M][TILE];       // 16 KB (256B rows, swizzled)
            short whb[2][FOUT][TILE];   // 16 KB (128B rows, swizzled)
            float sdl[CHUNK];           // 8 KB
        } s;                            // 40 KB -> 4 blocks/CU
        struct { float pC[2][M][FOUT]; float pD[2][M]; } e;  // 16.25 KB
    };
    __shared__ SMem sm;

    const int tid = threadIdx.x;
    const int w = tid >> 6, lane = tid & 63;
    const int m = lane & 15, kg = lane >> 4;
    const int wr = w >> 1, wc = w & 1;
    const int rg = blockIdx.x >> 2;
    const int c = blockIdx.x & 3;
    const int ibase = rg * M;
    const int cb = c * CHUNK;
    const int aRow = wr * 16 + m;
    const float ssrc = s_src[ibase + aRow];       // pre-scaled by log2e
    const int sidx = w * 2;                       // 2 staging instrs per wave/array

    f32x4 acc[4] = {{0,0,0,0},{0,0,0,0},{0,0,0,0},{0,0,0,0}};
    f32x4 acc4 = {0,0,0,0};                       // denominator accumulator
    const short oneb = (m == 0) ? (short)0x3F80 : (short)0;
    const bf16x8 bones = {oneb, oneb, oneb, oneb, oneb, oneb, oneb, oneb};

    // stage tile t into buf: 2 adj + 2 wh instrs per wave (uniform = 4)
    auto stage = [&](int t, int buf) {
        const int gcol = cb + t * TILE;
#pragma unroll
        for (int q = 0; q < 2; ++q) {          // adj: instr covers 4 rows (1 KB)
            const int idx = sidx + q;          // 0..7
            const int r = idx * 4 + (lane >> 4);
            const int b = ((lane & 15) * 16) ^ ((r & 15) << 4);   // byte in 256B row
            GLOAD_LDS16(adj + (size_t)(ibase + r) * N + gcol + (b >> 2),
                        &sm.s.adjb[buf][idx * 4][0]);
        }
#pragma unroll
        for (int q = 0; q < 2; ++q) {          // wh: instr covers 8 feat rows (1 KB)
            const int idx = sidx + q;          // 0..7
            const int f = idx * 8 + (lane >> 3);
            const int b = ((lane & 7) * 16) ^ ((f & 7) << 4);     // byte in 128B row
            GLOAD_LDS16(whT + (size_t)f * N + gcol + (b >> 1),
                        &sm.s.whb[buf][idx * 8][0]);
        }
    };

    // prologue: sdl chunk (2 instrs/wave = full 8 KB) + tile 0; drain; barrier
#pragma unroll
    for (int q = 0; q < 2; ++q) {
        const int i = sidx + q;                // 0..7 -> 8 x 256 floats = 2048
        GLOAD_LDS16(s_dst + cb + i * 256 + lane * 4, &sm.s.sdl[i * 256]);
    }
    stage(0, 0);
    asm volatile("s_waitcnt vmcnt(0)" ::: "memory");
    __builtin_amdgcn_s_barrier();

    for (int t = 0; t < NT; ++t) {
        const int buf = t & 1;
        if (t + 1 < NT) stage(t + 1, buf ^ 1);   // issue BEFORE compute

        // ---- compute tile t (LDS only) ----
        {
            const int kcol = wc * 32 + kg * 8;   // 0..56 within 64-col tile
            const char* adjbase = (const char*)&sm.s.adjb[buf][0][0];
            const int aswz = (aRow & 15) << 4;
            i32x4 a0 = *(const i32x4*)(adjbase + aRow * 256 + ((kcol * 4) ^ aswz));
            i32x4 a1 = *(const i32x4*)(adjbase + aRow * 256 + ((kcol * 4 + 16) ^ aswz));
            f32x4 d0 = *(const f32x4*)&sm.s.sdl[t * TILE + kcol];
            f32x4 d1 = *(const f32x4*)&sm.s.sdl[t * TILE + kcol + 4];
            const char* whbase = (const char*)&sm.s.whb[buf][0][0];
            const int wswz = (m & 7) << 4;
            bf16x8 bq0 = *(const bf16x8*)(whbase + (0 * 16 + m) * 128 + ((kcol * 2) ^ wswz));
            bf16x8 bq1 = *(const bf16x8*)(whbase + (1 * 16 + m) * 128 + ((kcol * 2) ^ wswz));
            bf16x8 bq2 = *(const bf16x8*)(whbase + (2 * 16 + m) * 128 + ((kcol * 2) ^ wswz));
            bf16x8 bq3 = *(const bf16x8*)(whbase + (3 * 16 + m) * 128 + ((kcol * 2) ^ wswz));

            float p[8];
#pragma unroll
            for (int e = 0; e < 4; ++e) {
                float x = ssrc + d0[e];
                float xl = fmaxf(x, 0.2f * x);
                float pe;
                asm("v_exp_f32 %0, %1" : "=v"(pe) : "v"(xl));
                p[e] = (a0[e] != 0) ? pe : 0.f;
            }
#pragma unroll
            for (int e = 0; e < 4; ++e) {
                float x = ssrc + d1[e];
                float xl = fmaxf(x, 0.2f * x);
                float pe;
                asm("v_exp_f32 %0, %1" : "=v"(pe) : "v"(xl));
                p[4 + e] = (a1[e] != 0) ? pe : 0.f;
            }
            union { bf16x8 v; unsigned u[4]; } afr;
#pragma unroll
            for (int q = 0; q < 4; ++q) {
                asm("v_cvt_pk_bf16_f32 %0, %1, %2"
                    : "=v"(afr.u[q]) : "v"(p[2 * q]), "v"(p[2 * q + 1]));
            }

            acc[0] = __builtin_amdgcn_mfma_f32_16x16x32_bf16(afr.v, bq0, acc[0], 0, 0, 0);
            acc[1] = __builtin_amdgcn_mfma_f32_16x16x32_bf16(afr.v, bq1, acc[1], 0, 0, 0);
            acc[2] = __builtin_amdgcn_mfma_f32_16x16x32_bf16(afr.v, bq2, acc[2], 0, 0, 0);
            acc[3] = __builtin_amdgcn_mfma_f32_16x16x32_bf16(afr.v, bq3, acc[3], 0, 0, 0);
            acc4   = __builtin_amdgcn_mfma_f32_16x16x32_bf16(afr.v, bones, acc4, 0, 0, 0);
        }

        // stage(t+1) had the whole compute phase to land; drain residue.
        asm volatile("s_waitcnt vmcnt(0)" ::: "memory");
        __builtin_amdgcn_s_barrier();
    }

    // epilogue (last barrier passed -> safe to reuse LDS)
#pragma unroll
    for (int r = 0; r < 4; ++r) {
#pragma unroll
        for (int q = 0; q < 4; ++q) {
            sm.e.pC[wc][wr * 16 + kg * 4 + r][q * 16 + m] = acc[q][r];
        }
    }
    if (m == 0) {   // den (col 0 of ones-MFMA): m==0 lanes, row kg*4+r
#pragma unroll
        for (int r = 0; r < 4; ++r) {
            sm.e.pD[wc][wr * 16 + kg * 4 + r] = acc4[r];
        }
    }
    __syncthreads();

    float* numC = numP + (size_t)c * N * FOUT;
    float* denC = denP + (size_t)c * N;
#pragma unroll
    for (int k = 0; k < 8; ++k) {
        int idx = k * 256 + tid;
        int i = idx >> 6, f = idx & 63;
        float num = sm.e.pC[0][i][f] + sm.e.pC[1][i][f];
        numC[(size_t)(ibase + i) * FOUT + f] = num;
        if (f == 0) {
            denC[ibase + i] = sm.e.pD[0][i] + sm.e.pD[1][i];
        }
    }
}

// Kernel 3: sum chunk partials, divide, ELU, store.
__global__ __launch_bounds__(256) void gat_combine(
    const float* __restrict__ numP, const float* __restrict__ denP,
    float* __restrict__ out) {
    int idx = blockIdx.x * 256 + threadIdx.x;
    int row = idx >> 6;
    float num = 0.f, den = 0.f;
#pragma unroll
    for (int cc = 0; cc < CSPLIT; ++cc) {
        num += numP[(size_t)cc * N * FOUT + idx];
        den += denP[(size_t)cc * N + row];
    }
    float v = num / den;
    out[idx] = (v > 0.f) ? v : expm1f(v);
}

extern "C" void kernel_launch(void* const* d_in, const int* in_sizes, int n_in,
                              void* d_out, int out_size, void* d_ws, size_t ws_size,
                              hipStream_t stream) {
    const float* h = (const float*)d_in[0];
    const int* adj = (const int*)d_in[1];
    const float* W = (const float*)d_in[2];
    const float* a = (const float*)d_in[3];
    float* out = (float*)d_out;

    char* ws = (char*)d_ws;
    __hip_bfloat16* whT = (__hip_bfloat16*)ws;                       // 1 MB
    float* s_src = (float*)(ws + (size_t)FOUT * N * sizeof(__hip_bfloat16));
    float* s_dst = s_src + N;                                        // +32 KB each
    float* numP = s_dst + N;                                         // 8 MB
    float* denP = numP + (size_t)CSPLIT * N * FOUT;                  // 128 KB

    hipLaunchKernelGGL(wh_kernel, dim3(N / 4), dim3(256), 0, stream,
                       h, W, a, whT, s_src, s_dst);
    hipLaunchKernelGGL(gat_partial, dim3((N / M) * CSPLIT), dim3(256), 0, stream,
                       adj, whT, s_src, s_dst, numP, denP);
    hipLaunchKernelGGL(gat_combine, dim3(N * FOUT / 256), dim3(256), 0, stream,
                       numP, denP, out);
}